// Round 5
// baseline (1219.772 us; speedup 1.0000x reference)
//
#include <hip/hip_runtime.h>
#include <hip/hip_bf16.h>

// Problem constants
#define NTOK 32768
#define CH   256
#define NEXP 16

typedef __attribute__((ext_vector_type(8)))  short short8;   // 8 x bf16 (4 VGPR)
typedef __attribute__((ext_vector_type(16))) float f32x16;   // MFMA 32x32 accumulator

#define MFMA32(a, b, c) __builtin_amdgcn_mfma_f32_32x32x16_bf16((a), (b), (c), 0, 0, 0)
#define BC8(v) __builtin_bit_cast(short8, (v))

// async global->LDS, 16B per lane; lds dst is wave-uniform base (+ lane*16 implicit)
#define GLD16(lds, g) __builtin_amdgcn_global_load_lds(                          \
    (const __attribute__((address_space(1))) unsigned int*)(g),                  \
    (__attribute__((address_space(3))) unsigned int*)(lds), 16, 0, 0)

// fp32 -> bf16 round-to-nearest-even
static __device__ __forceinline__ unsigned short f2bf(float f) {
  unsigned int u = __builtin_bit_cast(unsigned int, f);
  unsigned int r = (u + 0x7fffu + ((u >> 16) & 1u)) >> 16;
  return (unsigned short)r;
}
static __device__ __forceinline__ float bf2f(unsigned short h) {
  unsigned int u = ((unsigned int)h) << 16;
  return __builtin_bit_cast(float, u);
}

// ---------------------------------------------------------------------------
// Workspace layout (bytes):
//   [0,        16777216)  A_packed   N*C bf16, MFMA fragment order, per 64-tok tile
//   [16777216, 19005440)  W_packed   17*C*C bf16, MFMA fragment order
//   [19005440, 21102592)  combine    N*16 fp32
//   [21102592, 21168128)  frac_part  512*32 fp32
// ---------------------------------------------------------------------------

// Kernel 1: share_W (expert 16) + expert_W -> bf16 fragment order:
//   line (e, db, kb, lane) holds W[k = kb*16 + (lane>>5)*8 + j][d = db*32 + (lane&31)]
//   (same lane->(k,idx) map serves as A-operand (W^T) or B-operand fragment)
__global__ __launch_bounds__(256) void wconvert_kernel(
    const float* __restrict__ share_W, const float* __restrict__ expert_W,
    uint4* __restrict__ wp) {
  int g = blockIdx.x * 256 + threadIdx.x;   // 17*8192 lines
  int e = g >> 13;
  int r = g & 8191;
  int lane = r & 63;
  int kb = (r >> 6) & 15;
  int db = r >> 10;
  int d  = db * 32 + (lane & 31);
  int k0 = kb * 16 + ((lane >> 5) << 3);
  const float* src = (e < 16) ? (expert_W + (size_t)e * 65536) : share_W;
  unsigned int p[4];
#pragma unroll
  for (int j = 0; j < 4; j++) {
    float f0 = src[(size_t)(k0 + 2 * j) * 256 + d];
    float f1 = src[(size_t)(k0 + 2 * j + 1) * 256 + d];
    p[j] = (unsigned int)f2bf(f0) | ((unsigned int)f2bf(f1) << 16);
  }
  wp[g] = make_uint4(p[0], p[1], p[2], p[3]);
}

// Kernel 2 (unchanged from R3, passing): A fragment-pack + MFMA-based fp32 gating.
__global__ __launch_bounds__(256, 2) void gate_kernel(
    const float* __restrict__ inputs, const float* __restrict__ conv_out,
    const float* __restrict__ domain_emb, const float* __restrict__ gate_W,
    const float* __restrict__ gate_b, const float* __restrict__ ln_gamma,
    const float* __restrict__ ln_beta, uint4* __restrict__ apack,
    float* __restrict__ combine, float* __restrict__ frac_part) {
  __shared__ __align__(16) unsigned short tile[16384];  // 32 KB
  __shared__ __align__(16) uint4 gwh[1024];             // 16 KB
  __shared__ __align__(16) uint4 gwl[1024];             // 16 KB
  __shared__ float logit_s[2][512];
  __shared__ float fsc[2][2][32][16];
  int t = threadIdx.x, b = blockIdx.x;
  int w = t >> 6, l = t & 63;

#pragma unroll
  for (int i = 0; i < 4; i++) {
    int sidx = i * 256 + t;
    int kb = sidx >> 6, lane = sidx & 63;
    int col = lane & 31;
    int k0 = kb * 16 + ((lane >> 5) << 3);
    unsigned int hw[4] = {0, 0, 0, 0}, lw[4] = {0, 0, 0, 0};
    if (col < 16) {
#pragma unroll
      for (int j = 0; j < 4; j++) {
        float f0 = gate_W[(k0 + 2 * j) * 16 + col];
        float f1 = gate_W[(k0 + 2 * j + 1) * 16 + col];
        unsigned short h0 = f2bf(f0), h1 = f2bf(f1);
        unsigned short l0 = f2bf(f0 - bf2f(h0)), l1 = f2bf(f1 - bf2f(h1));
        hw[j] = (unsigned int)h0 | ((unsigned int)h1 << 16);
        lw[j] = (unsigned int)l0 | ((unsigned int)l1 << 16);
      }
    }
    gwh[sidx] = make_uint4(hw[0], hw[1], hw[2], hw[3]);
    gwl[sidx] = make_uint4(lw[0], lw[1], lw[2], lw[3]);
  }

  for (int i = 0; i < 8; i++) {
    int idx = i * 256 + t;
    int row = idx >> 5;
    int j = idx & 31;
    const float4* src = (const float4*)(inputs + ((size_t)b * 64 + row) * 256 + j * 8);
    float4 f0 = src[0], f1 = src[1];
    unsigned int p0 = (unsigned int)f2bf(f0.x) | ((unsigned int)f2bf(f0.y) << 16);
    unsigned int p1 = (unsigned int)f2bf(f0.z) | ((unsigned int)f2bf(f0.w) << 16);
    unsigned int p2 = (unsigned int)f2bf(f1.x) | ((unsigned int)f2bf(f1.y) << 16);
    unsigned int p3 = (unsigned int)f2bf(f1.z) | ((unsigned int)f2bf(f1.w) << 16);
    int s = j ^ (row & 31);
    *(uint4*)(tile + (row * 32 + s) * 8) = make_uint4(p0, p1, p2, p3);
  }
  __syncthreads();

  for (int i = 0; i < 8; i++) {
    int L = i * 256 + t;
    int ll = L & 63;
    int mb = (L >> 6) & 1, kb = L >> 7;
    int row = mb * 32 + (ll & 31);
    int j = kb * 2 + (ll >> 5);
    int s = j ^ (row & 31);
    apack[(size_t)b * 2048 + L] = *(const uint4*)(tile + (row * 32 + s) * 8);
  }

  int lc = l * 4;
  float4 g4 = *(const float4*)(ln_gamma + lc);
  float4 be4 = *(const float4*)(ln_beta + lc);
  float4 de4 = *(const float4*)(domain_emb + lc);
  unsigned int hp0[16], hp1[16], lp0[16], lp1[16];
#pragma unroll 1
  for (int i = 0; i < 16; i++) {
    int n = b * 64 + w * 16 + i;
    float4 x = *(const float4*)(conv_out + (size_t)n * 256 + lc);
    float a1 = x.x + x.y + x.z + x.w;
    float a2 = x.x * x.x + x.y * x.y + x.z * x.z + x.w * x.w;
#pragma unroll
    for (int off = 1; off < 64; off <<= 1) {
      a1 += __shfl_xor(a1, off);
      a2 += __shfl_xor(a2, off);
    }
    float mu = a1 * (1.f / 256.f);
    float var = a2 * (1.f / 256.f) - mu * mu;
    float rstd = rsqrtf(var + 1e-5f);
    float rx = (x.x - mu) * rstd * g4.x + be4.x + de4.x;
    float ry = (x.y - mu) * rstd * g4.y + be4.y + de4.y;
    float rz = (x.z - mu) * rstd * g4.z + be4.z + de4.z;
    float rw = (x.w - mu) * rstd * g4.w + be4.w + de4.w;
    unsigned short h0 = f2bf(rx), h1 = f2bf(ry), h2 = f2bf(rz), h3 = f2bf(rw);
    hp0[i] = (unsigned int)h0 | ((unsigned int)h1 << 16);
    hp1[i] = (unsigned int)h2 | ((unsigned int)h3 << 16);
    unsigned short e0 = f2bf(rx - bf2f(h0)), e1 = f2bf(ry - bf2f(h1));
    unsigned short e2 = f2bf(rz - bf2f(h2)), e3 = f2bf(rw - bf2f(h3));
    lp0[i] = (unsigned int)e0 | ((unsigned int)e1 << 16);
    lp1[i] = (unsigned int)e2 | ((unsigned int)e3 << 16);
  }
  __syncthreads();

  int jch = l >> 1;
  int half8 = (l & 1) * 4;
#pragma unroll
  for (int i = 0; i < 16; i++) {
    int n = w * 16 + i;
    int T = n >> 5, m = n & 31;
    unsigned short* dst = tile + T * 8192 + (m * 32 + (jch ^ m)) * 8 + half8;
    *(uint2*)dst = make_uint2(hp0[i], hp1[i]);
  }
  __syncthreads();

  f32x16 acc;
#pragma unroll
  for (int r = 0; r < 16; r++) acc[r] = 0.f;
  int m_ = l & 31, hf_ = l >> 5;
  if (w < 2) {
#pragma unroll
    for (int kb = 0; kb < 16; kb++) {
      int chunk = m_ * 32 + ((kb * 2 + hf_) ^ m_);
      short8 a = BC8(*(const uint4*)(tile + w * 8192 + chunk * 8));
      acc = MFMA32(a, BC8(gwh[kb * 64 + l]), acc);
      acc = MFMA32(a, BC8(gwl[kb * 64 + l]), acc);
    }
  }
  __syncthreads();

#pragma unroll
  for (int i = 0; i < 16; i++) {
    int n = w * 16 + i;
    int T = n >> 5, m = n & 31;
    unsigned short* dst = tile + T * 8192 + (m * 32 + (jch ^ m)) * 8 + half8;
    *(uint2*)dst = make_uint2(lp0[i], lp1[i]);
  }
  __syncthreads();

  if (w < 2) {
#pragma unroll
    for (int kb = 0; kb < 16; kb++) {
      int chunk = m_ * 32 + ((kb * 2 + hf_) ^ m_);
      short8 a = BC8(*(const uint4*)(tile + w * 8192 + chunk * 8));
      acc = MFMA32(a, BC8(gwh[kb * 64 + l]), acc);
      acc = MFMA32(a, BC8(gwl[kb * 64 + l]), acc);
    }
    int col = l & 31;
    if (col < 16) {
      float gb = gate_b[col];
#pragma unroll
      for (int r = 0; r < 16; r++) {
        int row = (r & 3) + ((r >> 2) << 3) + ((l >> 5) << 2);
        logit_s[w][row * 16 + col] = acc[r] + gb;
      }
    }
  }
  __syncthreads();

  if (w < 2 && l < 32) {
    int n = b * 64 + w * 32 + l;
    float lv[16];
#pragma unroll
    for (int q = 0; q < 4; q++)
      *(float4*)&lv[4 * q] = *(const float4*)&logit_s[w][l * 16 + 4 * q];
    float mx = lv[0];
#pragma unroll
    for (int e = 1; e < 16; e++) mx = fmaxf(mx, lv[e]);
    float p[16], sum = 0.f;
#pragma unroll
    for (int e = 0; e < 16; e++) { p[e] = expf(lv[e] - mx); sum += p[e]; }
    float inv = 1.f / sum;
    float wv[16], ent = 0.f;
#pragma unroll
    for (int e = 0; e < 16; e++) {
      wv[e] = p[e] * inv;
      ent -= wv[e] * logf(wv[e] + 1e-12f);
    }
    float kf = ceilf(1.f + ent * (15.f / 2.7725887f));
    int k = max(1, min(16, (int)kf));
    float cmb[16], selv[16];
#pragma unroll
    for (int e = 0; e < 16; e++) {
      int rk = 0;
#pragma unroll
      for (int j2 = 0; j2 < 16; j2++)
        rk += (int)((wv[j2] > wv[e]) || (wv[j2] == wv[e] && j2 < e));
      int sel = rk < k;
      cmb[e] = sel ? wv[e] : 0.f;
      selv[e] = sel ? 1.f : 0.f;
    }
#pragma unroll
    for (int q = 0; q < 4; q++) {
      *(float4*)&combine[(size_t)n * 16 + 4 * q] = *(float4*)&cmb[4 * q];
      *(float4*)&fsc[0][w][l][4 * q] = *(float4*)&selv[4 * q];
      *(float4*)&fsc[1][w][l][4 * q] = *(float4*)&wv[4 * q];
    }
  }
  __syncthreads();

  if (t < 32) {
    int kind = t >> 4, e = t & 15;
    float ssum = 0.f;
    for (int T2 = 0; T2 < 2; T2++)
      for (int tok = 0; tok < 32; tok++)
        ssum += fsc[kind][T2][tok][e];
    frac_part[b * 32 + t] = ssum;
  }
}

// Kernel 3 (v5.1): TRANSPOSED MFMA — tokens are the B operand (C/D col = token),
// W^T is the A operand. Combine weight is a per-lane scalar. W streams
// global->VGPR (each wave owns one 32-col d-group: zero duplication, 2.2 MB/CU
// TCP pole ~16 µs). NO barriers in the 68-slot loop.
// R4 FIX: wt2 fill was [e][ng][tk] but read as [e][tk][ng] -> scrambled combine
// weights (absmax 1.89). Now written as [e][tk][ng] to match the float4 read.
__global__ __launch_bounds__(512, 2) void moe_gemm_kernel(
    const uint4* __restrict__ apack, const uint4* __restrict__ wpack,
    const float* __restrict__ combine, const float* __restrict__ expert_b,
    const float* __restrict__ share_b, float* __restrict__ out) {
  extern __shared__ __align__(16) char smem[];
  uint4* atile = (uint4*)smem;                     // 64 KB token frags
  float* wt2   = (float*)(smem + 65536);           // [17][32][4] = 8704 B (e16 = 1.0)
  unsigned int* craw2 = (unsigned int*)(smem + 65536 + 8704); // [128][8] bf16-packed, 4 KB
  float* tbuf  = (float*)smem;                     // epilogue transpose, 64*260*4 B

  int t = threadIdx.x, b = blockIdx.x;
  int w = t >> 6, l = t & 63;
  int tk = l & 31, hf = l >> 5;
  int rowoff = hf * 4;

  // ---- staging (once) ----
#pragma unroll
  for (int i = 0; i < 8; i++) {
    int g = w * 8 + i;               // line g = kb*4 + ng
    int kb = g >> 2, ng = g & 3;
    GLD16(atile + g * 64,
          apack + ((size_t)(2 * b + (ng >> 1)) * 2048 + (size_t)(kb * 2 + (ng & 1)) * 64 + l));
  }
  // wt2[e][tk][ng]: fp32 combine weights (expert 16 -> 1.0).
  // token n = b*128 + ng*32 + tk  (matches atile ng-group token mapping)
  for (int i = 0; i < 5; i++) {
    int idx = i * 512 + t;
    if (idx < 2176) {
      int e = idx >> 7, rem = idx & 127;
      int ng = rem & 3, tkk = rem >> 2;
      wt2[idx] = (e < 16) ? combine[((size_t)b * 128 + ng * 32 + tkk) * 16 + e] : 1.0f;
    }
  }
  // craw2: combine bf16-packed per token (for the bias MFMA B-fragment)
  {
    int tok = t >> 2, part = t & 3;
    float4 c = *(const float4*)&combine[((size_t)b * 128 + tok) * 16 + part * 4];
    unsigned int p0 = (unsigned int)f2bf(c.x) | ((unsigned int)f2bf(c.y) << 16);
    unsigned int p1 = (unsigned int)f2bf(c.z) | ((unsigned int)f2bf(c.w) << 16);
    *(uint2*)&craw2[tok * 8 + part * 2] = make_uint2(p0, p1);
  }
  __syncthreads();   // drains GLD; LDS read-only until epilogue

  f32x16 facc[4], zc;
#pragma unroll
  for (int r = 0; r < 16; r++) zc[r] = 0.f;
#pragma unroll
  for (int ng = 0; ng < 4; ng++)
#pragma unroll
    for (int r = 0; r < 16; r++) facc[ng][r] = 0.f;

  const uint4* wl = wpack + (size_t)w * 1024 + l;   // this wave's d-group stream
  uint4 wf[4], wfn[4];
#pragma unroll
  for (int kbl = 0; kbl < 4; kbl++) wf[kbl] = wl[kbl * 64];   // slot 0 (q=0,e=0)

  int s = 0;
  for (int q = 0; q < 4; q++) {
    // token fragments for this quarter: register-stationary across 17 experts
    short8 breg[4][4];
#pragma unroll
    for (int kbl = 0; kbl < 4; kbl++)
#pragma unroll
      for (int ng = 0; ng < 4; ng++)
        breg[ng][kbl] = BC8(atile[((size_t)(q * 4 + kbl) * 4 + ng) * 64 + l]);

    for (int e = 0; e < 17; e++, s++) {
      // prefetch next slot's W (global->VGPR, flies across the MFMA block)
      if (s < 67) {
        int en = (e == 16) ? 0 : e + 1;
        int qn = (e == 16) ? q + 1 : q;
#pragma unroll
        for (int kbl = 0; kbl < 4; kbl++)
          wfn[kbl] = wl[(size_t)en * 8192 + (qn * 4 + kbl) * 64];
      }
      // per-lane combine weights for this expert (col = token!)
      float4 wv4 = *(const float4*)&wt2[e * 128 + tk * 4];

#pragma unroll
      for (int ng = 0; ng < 4; ng++) {
        f32x16 tacc = MFMA32(BC8(wf[0]), breg[ng][0], zc);
        tacc = MFMA32(BC8(wf[1]), breg[ng][1], tacc);
        tacc = MFMA32(BC8(wf[2]), breg[ng][2], tacc);
        tacc = MFMA32(BC8(wf[3]), breg[ng][3], tacc);
        float wvs = (ng == 0) ? wv4.x : (ng == 1) ? wv4.y : (ng == 2) ? wv4.z : wv4.w;
#pragma unroll
        for (int r = 0; r < 16; r++) facc[ng][r] += wvs * tacc[r];
      }
      if (s < 67) {
#pragma unroll
        for (int kbl = 0; kbl < 4; kbl++) wf[kbl] = wfn[kbl];
      }
    }
  }

  // ---- bias: facc += (eb^T x combine^T) via one MFMA per ng + share_b ----
  {
    unsigned int ebp[4];
#pragma unroll
    for (int j2 = 0; j2 < 4; j2++) {
      float e0 = expert_b[(hf * 8 + 2 * j2) * 256 + w * 32 + tk];
      float e1 = expert_b[(hf * 8 + 2 * j2 + 1) * 256 + w * 32 + tk];
      ebp[j2] = (unsigned int)f2bf(e0) | ((unsigned int)f2bf(e1) << 16);
    }
    short8 ebf = BC8(make_uint4(ebp[0], ebp[1], ebp[2], ebp[3]));
#pragma unroll
    for (int ng = 0; ng < 4; ng++) {
      uint4 cw = *(const uint4*)&craw2[(ng * 32 + tk) * 8 + hf * 4];
      facc[ng] = MFMA32(ebf, BC8(cw), facc[ng]);
    }
    // share_b
#pragma unroll
    for (int rg = 0; rg < 4; rg++) {
      float4 s4 = *(const float4*)&share_b[w * 32 + rg * 8 + rowoff];
#pragma unroll
      for (int ng = 0; ng < 4; ng++) {
        facc[ng][rg * 4 + 0] += s4.x;
        facc[ng][rg * 4 + 1] += s4.y;
        facc[ng][rg * 4 + 2] += s4.z;
        facc[ng][rg * 4 + 3] += s4.w;
      }
    }
  }

  // ---- epilogue: LDS transpose (two 64-token halves), coalesced stores ----
#pragma unroll 1
  for (int h = 0; h < 2; h++) {
    __syncthreads();   // h=0: everyone done with atile/wt2/craw2; h=1: tbuf reads done
#pragma unroll
    for (int ng2 = 0; ng2 < 2; ng2++) {
      int ng = h * 2 + ng2;
#pragma unroll
      for (int r = 0; r < 16; r++) {
        int d = w * 32 + (r & 3) + ((r >> 2) << 3) + rowoff;
        tbuf[(ng2 * 32 + tk) * 260 + d] = facc[ng][r];
      }
    }
    __syncthreads();
#pragma unroll
    for (int i = 0; i < 8; i++) {
      int idx = i * 512 + t;
      int tok = idx >> 6, g = idx & 63;
      float4 v = *(const float4*)&tbuf[tok * 260 + g * 4];
      *(float4*)&out[((size_t)b * 128 + h * 64 + tok) * 256 + g * 4] = v;
    }
  }
}

// Kernel 4: reduce balance-loss partials -> scalar at d_out[N*C]
__global__ __launch_bounds__(256) void finalize_kernel(
    const float* __restrict__ frac_part, float* __restrict__ loss_out) {
  __shared__ float acc[8][32];
  int t = threadIdx.x;
  int col = t & 31, seg = t >> 5;
  float s = 0.f;
  for (int i = seg; i < 512; i += 8) s += frac_part[i * 32 + col];
  acc[seg][col] = s;
  __syncthreads();
  if (t < 32) {
    float v = 0.f;
#pragma unroll
    for (int sg = 0; sg < 8; sg++) v += acc[sg][t];
    acc[0][t] = v;
  }
  __syncthreads();
  if (t == 0) {
    float loss = 0.f;
    for (int e = 0; e < 16; e++) {
      float ft = acc[0][e] * (1.f / 32768.f);
      float fp = acc[0][16 + e] * (1.f / 32768.f);
      loss += ft * fp;
    }
    loss_out[0] = loss * 16.f;
  }
}

extern "C" void kernel_launch(void* const* d_in, const int* in_sizes, int n_in,
                              void* d_out, int out_size, void* d_ws, size_t ws_size,
                              hipStream_t stream) {
  const float* inputs   = (const float*)d_in[0];
  const float* conv_out = (const float*)d_in[1];
  const float* demb     = (const float*)d_in[2];
  const float* share_W  = (const float*)d_in[3];
  const float* share_b  = (const float*)d_in[4];
  const float* gate_W   = (const float*)d_in[5];
  const float* gate_b   = (const float*)d_in[6];
  const float* expert_W = (const float*)d_in[7];
  const float* expert_b = (const float*)d_in[8];
  const float* ln_g     = (const float*)d_in[9];
  const float* ln_b     = (const float*)d_in[10];
  float* out = (float*)d_out;
  char* ws = (char*)d_ws;

  uint4* apack   = (uint4*)(ws);
  uint4* wpack   = (uint4*)(ws + 16777216);
  float* combine = (float*)(ws + 19005440);
  float* frac    = (float*)(ws + 21102592);

  // 78336 B dynamic LDS (64K atile + 8704 wt2 + 4096 craw2; tbuf overlaps)
  hipFuncSetAttribute((const void*)moe_gemm_kernel,
                      hipFuncAttributeMaxDynamicSharedMemorySize, 78336);

  wconvert_kernel<<<dim3(544), dim3(256), 0, stream>>>(share_W, expert_W, wpack);
  gate_kernel<<<dim3(512), dim3(256), 0, stream>>>(inputs, conv_out, demb, gate_W,
                                                   gate_b, ln_g, ln_b, apack, combine, frac);
  moe_gemm_kernel<<<dim3(256), dim3(512), 78336, stream>>>(apack, wpack, combine,
                                                           expert_b, share_b, out);
  finalize_kernel<<<dim3(1), dim3(256), 0, stream>>>(frac, out + 8388608);
}